// Round 10
// baseline (227.906 us; speedup 1.0000x reference)
//
#include <hip/hip_runtime.h>
#include <hip/hip_fp16.h>
#include <math.h>

#define N_NODES 100000
#define N_EDGES 1600000
#define RR      6
#define CIN     8
#define COUT    16
#define EPS     1e-8f

#define NBLK_A  512
#define ABLOCK  1024
#define CHUNK   (N_EDGES / NBLK_A)      // 3125 (exact)

// region key = dst >> 7  (128 nodes per region)
#define NKEY    782                     // ceil(100000/128)
#define QCAP3   2304                    // per-region cap (mean 2048, +5.7 sigma)
#define QCAPH   1280                    // per-HALF cap (mean 1024, +8 sigma)

// ---- partition dynamic LDS layout (UNCHANGED) -----------------------------
#define LDS_SPAY   0
#define LDS_SHDR   75000
#define LDS_SBKT   87500
#define LDS_CNT    93752
#define LDS_TOTAL  106368

// float pair -> packed fp16x2 (RNE)
__device__ inline unsigned int pack_f16(float a, float b) {
    __half2 h = __floats2half2_rn(a, b);
    return *(unsigned int*)&h;
}

// ---------------------------------------------------------------------------
// Phase A v4 (unchanged): counting sort by dst>>7 into 782 dense runs.
// ---------------------------------------------------------------------------
__global__ __launch_bounds__(ABLOCK)
void partition_kernel(const int* __restrict__ edges,
                      const float* __restrict__ sten,
                      int* __restrict__ gcur,
                      unsigned int* __restrict__ hdr,
                      unsigned int* __restrict__ pay) {
    extern __shared__ char smem[];
    uint2*          spay = (uint2*)(smem + LDS_SPAY);
    unsigned int*   shdr = (unsigned int*)(smem + LDS_SHDR);
    unsigned short* sbkt = (unsigned short*)(smem + LDS_SBKT);
    int* cnt   = (int*)(smem + LDS_CNT);
    int* cur   = cnt + NKEY;
    int* base  = cur + NKEY;
    int* gbase = base + NKEY;

    int tid = threadIdx.x;
    int blk = blockIdx.x;
    int e0 = blk * CHUNK;

    for (int i = tid; i < NKEY; i += ABLOCK) { cnt[i] = 0; cur[i] = 0; }
    __syncthreads();

    for (int i = tid; i < CHUNK; i += ABLOCK) {
        int2 ed = ((const int2*)edges)[e0 + i];
        atomicAdd(&cnt[ed.y >> 7], 1);
    }
    __syncthreads();

    if (tid < 64) {
        int lane = tid;
        int off = 0;
        for (int c = 0; c < NKEY; c += 64) {
            int idx = c + lane;
            int v = (idx < NKEY) ? cnt[idx] : 0;
            int orig = v;
#pragma unroll
            for (int d = 1; d < 64; d <<= 1) {
                int t = __shfl_up(v, d);
                if (lane >= d) v += t;
            }
            if (idx < NKEY) base[idx] = off + v - orig;
            off += __shfl(v, 63);
        }
    }
    __syncthreads();

    for (int b = tid; b < NKEY; b += ABLOCK) {
        int c = cnt[b];
        gbase[b] = (c > 0) ? atomicAdd(&gcur[b], c) : 0;
    }
    __syncthreads();

    for (int i = tid; i < CHUNK; i += ABLOCK) {
        int e = e0 + i;
        int2 ed = ((const int2*)edges)[e];
        int b = ed.y >> 7;
        int p = base[b] + atomicAdd(&cur[b], 1);
        sbkt[p] = (unsigned short)b;
        shdr[p] = ((unsigned int)ed.x << 8) | (unsigned int)(ed.y & 255);
        const float4* sp = (const float4*)(sten + (size_t)e * 12);
        float4 s0 = sp[0], s1 = sp[1], s2 = sp[2];
        uint2* dp = spay + p * 3;
        dp[0] = (uint2){ pack_f16(s0.x, s0.y), pack_f16(s0.z, s0.w) };
        dp[1] = (uint2){ pack_f16(s1.x, s1.y), pack_f16(s1.z, s1.w) };
        dp[2] = (uint2){ pack_f16(s2.x, s2.y), pack_f16(s2.z, s2.w) };
    }
    __syncthreads();

    for (int p = tid; p < CHUNK; p += ABLOCK) {
        int b = (int)sbkt[p];
        int rel = p - base[b];
        long long slot = (long long)gbase[b] + rel;
        if (slot < QCAP3) {
            size_t rs = (size_t)b * QCAP3 + slot;
            hdr[rs] = shdr[p];
            const uint2* sp = spay + p * 3;
            uint2 w0 = sp[0], w1 = sp[1], w2 = sp[2];
            unsigned int* dp = pay + rs * 6;
            *(uint2*)(dp + 0) = w0;
            *(uint2*)(dp + 2) = w1;
            *(uint2*)(dp + 4) = w2;
        }
    }
}

// ---------------------------------------------------------------------------
// Phase B v10: HALF-region blocks (64 nodes, 256 threads, grid 1564).
// 1564 blocks x 4 waves = 6256 waves = 24.4/CU -> ENTIRE grid co-resident
// (zero multi-round tail, the r9 bottleneck at 28% occupancy).
//  - global gather walk + dense warm pass (r9's proven structure)
//  - headers scanned 2x/region (8KB, L2-hot); warm 2x (2nd is L3-hit)
//  - degree-sorted node->wave assignment (64-elem bitonic)
// LDS ~12.4KB static -> 8 blocks/CU (wave-capped), not LDS-capped.
// ---------------------------------------------------------------------------
__global__ __launch_bounds__(256, 4)
void bucket_kernel(const float* __restrict__ x,
                   const float* __restrict__ weight,
                   const float* __restrict__ offset,
                   const float* __restrict__ bias,
                   const int* __restrict__ gcur,
                   const unsigned int* __restrict__ hdr,
                   const unsigned int* __restrict__ pay,
                   float* __restrict__ out) {
    __shared__ unsigned int idxs[QCAPH];        // 5120 B: (src<<12) | j
    __shared__ float fre[RR * CIN * COUT];
    __shared__ float fim[RR * CIN * COUT];
    __shared__ int cnt[64], nbase[64], cur2[64];
    __shared__ float bsh[COUT];
    __shared__ unsigned int perm[64];

    int tid  = threadIdx.x;
    int key  = blockIdx.x >> 1;
    int half = blockIdx.x & 1;

    for (int i = tid; i < RR * CIN * COUT; i += 256) {
        int co = i % (CIN * COUT);              // offset is (CIN, COUT)
        float w = weight[i], off = offset[co];
        fre[i] = w * cosf(off);
        fim[i] = w * sinf(off);
    }
    if (tid < COUT) bsh[tid] = bias[tid];
    if (tid < 64) { cnt[tid] = 0; cur2[tid] = 0; }
    __syncthreads();

    int T = gcur[key];
    if (T > QCAP3) T = QCAP3;

    const unsigned int* hslice = hdr + (size_t)key * QCAP3;
    const uint2* psrc = (const uint2*)(pay + (size_t)key * QCAP3 * 6);

    // warm pass: dense sequential read of the pay region -> own-XCD L2.
    // (region is L3-resident, so the sibling block's warm is an L3 hit)
    for (int i = tid; i < T * 3; i += 256) {
        uint2 v = psrc[i];
        asm volatile("" :: "v"(v.x), "v"(v.y));
    }

    // pass 1: count this half's nodes (dense header read)
    for (int j = tid; j < T; j += 256) {
        unsigned int h = hslice[j];
        int d = (int)(h & 127u);
        if ((d >> 6) == half) atomicAdd(&cnt[d & 63], 1);
    }
    __syncthreads();

    // exclusive scan of 64 counters (wave 0)
    if (tid < 64) {
        int v = cnt[tid];
        int orig = v;
#pragma unroll
        for (int d = 1; d < 64; d <<= 1) {
            int t = __shfl_up(v, d);
            if (tid >= d) v += t;
        }
        nbase[tid] = v - orig;
    }
    __syncthreads();

    // pass 2: place packed (src<<12)|j per node (headers L1-hot)
    for (int j = tid; j < T; j += 256) {
        unsigned int h = hslice[j];
        int d = (int)(h & 127u);
        if ((d >> 6) == half) {
            int pos = nbase[d & 63] + atomicAdd(&cur2[d & 63], 1);
            if (pos < QCAPH)
                idxs[pos] = ((h >> 8) << 12) | (unsigned int)j;
        }
    }

    // degree-sort: perm[i] = (deg<<8)|local, 64-elem bitonic (ascending)
    if (tid < 64) perm[tid] = ((unsigned int)cnt[tid] << 8) | (unsigned int)tid;
    __syncthreads();
    for (int k2 = 2; k2 <= 64; k2 <<= 1) {
        for (int jj = k2 >> 1; jj > 0; jj >>= 1) {
            if (tid < 64) {
                int ixj = tid ^ jj;
                if (ixj > tid) {
                    unsigned int a = perm[tid], c = perm[ixj];
                    bool up = ((tid & k2) == 0);
                    if (up ? (a > c) : (a < c)) { perm[tid] = c; perm[ixj] = a; }
                }
            }
            __syncthreads();
        }
    }

    // walk: rank -> node via perm; wave handles 16 similar-degree nodes;
    // payload gathered from global (L1/L2-hot after warm pass)
    int rank = tid >> 2;
    int l = tid & 3;
    unsigned int pk0 = perm[rank];
    int local = (int)(pk0 & 255u) & 63;
    int deg   = (int)(pk0 >> 8);
    int base  = nbase[local];
    if (base + deg > QCAPH) deg = (base < QCAPH) ? (QCAPH - base) : 0;
    int n = key * 128 + half * 64 + local;
    if (n >= N_NODES) return;                  // no barriers after this point

    float ar[RR][2] = {};
    float ai[RR][2] = {};

    uint2 p0 = {}, p1 = {}, p2 = {};
    float2 xv = {};
    if (deg > 0) {
        unsigned int pk = idxs[base];
        int j   = (int)(pk & 4095u);
        int src = (int)(pk >> 12);
        const uint2* pp = psrc + j * 3;
        p0 = pp[0]; p1 = pp[1]; p2 = pp[2];
        xv = *(const float2*)(x + (size_t)src * CIN + 2 * l);
    }
    for (int k = 0; k < deg; ++k) {
        uint2 q0 = {}, q1 = {}, q2 = {};
        float2 nx = {};
        if (k + 1 < deg) {
            unsigned int pk = idxs[base + k + 1];
            int j   = (int)(pk & 4095u);
            int src = (int)(pk >> 12);
            const uint2* pp = psrc + j * 3;
            q0 = pp[0]; q1 = pp[1]; q2 = pp[2];
            nx = *(const float2*)(x + (size_t)src * CIN + 2 * l);
        }
        unsigned int wv[6] = {p0.x, p0.y, p1.x, p1.y, p2.x, p2.y};
#pragma unroll
        for (int r = 0; r < RR; ++r) {
            __half2 hh = *(__half2*)&wv[r];
            float sre = __half2float(__low2half(hh));
            float sim = __half2float(__high2half(hh));
            ar[r][0] = fmaf(sre, xv.x, ar[r][0]);
            ar[r][1] = fmaf(sre, xv.y, ar[r][1]);
            ai[r][0] = fmaf(sim, xv.x, ai[r][0]);
            ai[r][1] = fmaf(sim, xv.y, ai[r][1]);
        }
        p0 = q0; p1 = q1; p2 = q2; xv = nx;
    }

    float yr[COUT], yi[COUT];
#pragma unroll
    for (int o = 0; o < COUT; ++o) { yr[o] = 0.f; yi[o] = 0.f; }
#pragma unroll
    for (int r = 0; r < RR; ++r) {
#pragma unroll
        for (int j = 0; j < 2; ++j) {
            int c = 2 * l + j;
            float are = ar[r][j], aim = ai[r][j];
            const float* fr = &fre[(r * CIN + c) * COUT];
            const float* fi = &fim[(r * CIN + c) * COUT];
#pragma unroll
            for (int o = 0; o < COUT; ++o) {
                yr[o] = fmaf(are, fr[o], yr[o]);
                yr[o] = fmaf(-aim, fi[o], yr[o]);
                yi[o] = fmaf(are, fi[o], yi[o]);
                yi[o] = fmaf(aim, fr[o], yi[o]);
            }
        }
    }
#pragma unroll
    for (int o = 0; o < COUT; ++o) {
        yr[o] += __shfl_xor(yr[o], 1);
        yr[o] += __shfl_xor(yr[o], 2);
        yi[o] += __shfl_xor(yi[o], 1);
        yi[o] += __shfl_xor(yi[o], 2);
    }
    float tmp[8];
    int ob = 4 * l;
#pragma unroll
    for (int j = 0; j < 4; ++j) {
        int o = ob + j;
        float re = yr[o], im = yi[o];
        float mag = sqrtf(re * re + im * im);
        float sc = fmaxf(mag + bsh[o], 0.f) / (mag + EPS);
        tmp[2 * j]     = re * sc;
        tmp[2 * j + 1] = im * sc;
    }
    float4* op = (float4*)(out + (size_t)n * 2 * COUT + 8 * l);
    op[0] = ((const float4*)tmp)[0];
    op[1] = ((const float4*)tmp)[1];
}

extern "C" void kernel_launch(void* const* d_in, const int* in_sizes, int n_in,
                              void* d_out, int out_size, void* d_ws, size_t ws_size,
                              hipStream_t stream) {
    const float* x      = (const float*)d_in[0];
    const int*   edges  = (const int*)d_in[1];
    const float* sten   = (const float*)d_in[2];
    const float* weight = (const float*)d_in[3];
    const float* offset = (const float*)d_in[4];
    const float* bias   = (const float*)d_in[5];
    float* out = (float*)d_out;

    // ws: gcur (8 KB) | hdr (NKEY*QCAP3*4B = 7.2 MB) | pay (NKEY*QCAP3*24B = 43.2 MB)
    int* gcur = (int*)d_ws;
    unsigned int* hdr = (unsigned int*)((char*)d_ws + 8192);
    unsigned int* pay = hdr + (size_t)NKEY * QCAP3;

    static int lds_inited = 0;
    if (!lds_inited) {
        (void)hipFuncSetAttribute((const void*)partition_kernel,
                                  hipFuncAttributeMaxDynamicSharedMemorySize,
                                  LDS_TOTAL);
        lds_inited = 1;
    }

    (void)hipMemsetAsync(gcur, 0, sizeof(int) * NKEY, stream);

    partition_kernel<<<NBLK_A, ABLOCK, LDS_TOTAL, stream>>>(edges, sten, gcur, hdr, pay);
    bucket_kernel<<<NKEY * 2, 256, 0, stream>>>(x, weight, offset, bias,
                                                gcur, hdr, pay, out);
}